// Round 6
// baseline (169.511 us; speedup 1.0000x reference)
//
#include <hip/hip_runtime.h>

// Problem: y[b,c,0,h,w] = x[b,c,0,h,w]
//          y[b,c,n,h,w] = 0.3*x[b,c,n,h,w] + 0.7*y[b,c,n-1,h,w]
// Shapes: x,y = [4, 3, 32, 256, 256] fp32. Recurrence along axis 2 (N=32).
//
// v6 = v5 (NT loads+stores, segmented scan, LDS closure) + 2 chains/thread.
// History: v1-v4 (occupancy/ILP/barrier/persistence variants) all ~60 us;
// v5 NT loads -> ~52 us (cache-allocation tax on reads was real).
// Remaining 52-vs-32us gap theory: DRAM row-buffer thrash on the read path.
// A 256KB frame stride leaves channel bits unchanged -> each thread's 8
// loads hit the same channels with 8 different rows; the copy kernel that
// achieves 6.29 TB/s walks sequential addresses instead. This version gives
// each thread chains c and c+64, so every frame-plane is covered by two
// back-to-back wave-loads at CONSECUTIVE addresses: contiguous 2KB runs
// (2x run length, half the stream count). If neutral -> declare ceiling.
// Closure math identical to v2-v5 (absmax 0.0078125):
//   carry(s) = e[s-1] + 0.7^8*e[s-2] + 0.7^16*e[s-3]; y[n] = p[n] + 0.7^(n+1)*carry

typedef float vf4 __attribute__((ext_vector_type(4)));

constexpr int   NFR = 32;               // frames
constexpr int   HW4 = (256 * 256) / 4;  // float4 per frame-plane (16384 = 2^14)
constexpr int   FPS = 8;                // frames per segment
constexpr int   CPB = 128;              // chains per block (64 lanes x 2 chains x ... )
constexpr float WF  = 0.3f;
constexpr float OMW = 0.7f;

constexpr float P1  = 0.7f;
constexpr float P2  = P1 * 0.7f;
constexpr float P3  = P2 * 0.7f;
constexpr float P4  = P3 * 0.7f;
constexpr float P5  = P4 * 0.7f;
constexpr float P6  = P5 * 0.7f;
constexpr float P7  = P6 * 0.7f;
constexpr float P8  = P7 * 0.7f;
constexpr float P16 = P8 * P8;

__global__ __launch_bounds__(256) void recfilt_kernel(const vf4* __restrict__ x,
                                                      vf4* __restrict__ y) {
    const int tid = threadIdx.x;
    const int t   = tid & 63;          // lane = chain-pair slot
    const int seg = tid >> 6;          // 0..3, wave-uniform
    const int q   = blockIdx.x * CPB + t;      // chain A id; chain B = q + 64
    const int bc  = q >> 14;                   // q / HW4 (CPB | HW4 -> bc uniform)
    const int hw  = q & (HW4 - 1);
    const int base = bc * (NFR * HW4) + seg * (FPS * HW4) + hw;   // int32 ok

    // ---- 16 NT loads; a_n and b_n are consecutive 1KB wave-footprints ----
    // (pair covers a contiguous 2KB run of each frame-plane)
    vf4 a0 = __builtin_nontemporal_load(&x[base + 0 * HW4]);
    vf4 b0 = __builtin_nontemporal_load(&x[base + 0 * HW4 + 64]);
    vf4 a1 = __builtin_nontemporal_load(&x[base + 1 * HW4]);
    vf4 b1 = __builtin_nontemporal_load(&x[base + 1 * HW4 + 64]);
    vf4 a2 = __builtin_nontemporal_load(&x[base + 2 * HW4]);
    vf4 b2 = __builtin_nontemporal_load(&x[base + 2 * HW4 + 64]);
    vf4 a3 = __builtin_nontemporal_load(&x[base + 3 * HW4]);
    vf4 b3 = __builtin_nontemporal_load(&x[base + 3 * HW4 + 64]);
    vf4 a4 = __builtin_nontemporal_load(&x[base + 4 * HW4]);
    vf4 b4 = __builtin_nontemporal_load(&x[base + 4 * HW4 + 64]);
    vf4 a5 = __builtin_nontemporal_load(&x[base + 5 * HW4]);
    vf4 b5 = __builtin_nontemporal_load(&x[base + 5 * HW4 + 64]);
    vf4 a6 = __builtin_nontemporal_load(&x[base + 6 * HW4]);
    vf4 b6 = __builtin_nontemporal_load(&x[base + 6 * HW4 + 64]);
    vf4 a7 = __builtin_nontemporal_load(&x[base + 7 * HW4]);
    vf4 b7 = __builtin_nontemporal_load(&x[base + 7 * HW4 + 64]);

    // ---- local prefix (two independent chains -> 2x FMA ILP) ----
    if (seg != 0) { a0 *= WF; b0 *= WF; }
    a1 = WF * a1 + OMW * a0;   b1 = WF * b1 + OMW * b0;
    a2 = WF * a2 + OMW * a1;   b2 = WF * b2 + OMW * b1;
    a3 = WF * a3 + OMW * a2;   b3 = WF * b3 + OMW * b2;
    a4 = WF * a4 + OMW * a3;   b4 = WF * b4 + OMW * b3;
    a5 = WF * a5 + OMW * a4;   b5 = WF * b5 + OMW * b4;
    a6 = WF * a6 + OMW * a5;   b6 = WF * b6 + OMW * b5;
    a7 = WF * a7 + OMW * a6;   b7 = WF * b7 + OMW * b6;

    // ---- publish segment-end partials, close the carry chain ----
    __shared__ vf4 lend[3][CPB];
    if (seg < 3) { lend[seg][t] = a7; lend[seg][t + 64] = b7; }
    __syncthreads();

    vf4 ca = (vf4)(0.0f), cb = (vf4)(0.0f);
    if (seg == 1) {
        ca = lend[0][t];
        cb = lend[0][t + 64];
    } else if (seg == 2) {
        ca = lend[1][t] + P8 * lend[0][t];
        cb = lend[1][t + 64] + P8 * lend[0][t + 64];
    } else if (seg == 3) {
        ca = (lend[2][t] + P8 * lend[1][t]) + P16 * lend[0][t];
        cb = (lend[2][t + 64] + P8 * lend[1][t + 64]) + P16 * lend[0][t + 64];
    }

    // ---- y[n] = p[n] + 0.7^(n+1) * carry ; NT stores, paired 2KB runs ----
    vf4 o;
    o = a0 + P1 * ca; __builtin_nontemporal_store(o, &y[base + 0 * HW4]);
    o = b0 + P1 * cb; __builtin_nontemporal_store(o, &y[base + 0 * HW4 + 64]);
    o = a1 + P2 * ca; __builtin_nontemporal_store(o, &y[base + 1 * HW4]);
    o = b1 + P2 * cb; __builtin_nontemporal_store(o, &y[base + 1 * HW4 + 64]);
    o = a2 + P3 * ca; __builtin_nontemporal_store(o, &y[base + 2 * HW4]);
    o = b2 + P3 * cb; __builtin_nontemporal_store(o, &y[base + 2 * HW4 + 64]);
    o = a3 + P4 * ca; __builtin_nontemporal_store(o, &y[base + 3 * HW4]);
    o = b3 + P4 * cb; __builtin_nontemporal_store(o, &y[base + 3 * HW4 + 64]);
    o = a4 + P5 * ca; __builtin_nontemporal_store(o, &y[base + 4 * HW4]);
    o = b4 + P5 * cb; __builtin_nontemporal_store(o, &y[base + 4 * HW4 + 64]);
    o = a5 + P6 * ca; __builtin_nontemporal_store(o, &y[base + 5 * HW4]);
    o = b5 + P6 * cb; __builtin_nontemporal_store(o, &y[base + 5 * HW4 + 64]);
    o = a6 + P7 * ca; __builtin_nontemporal_store(o, &y[base + 6 * HW4]);
    o = b6 + P7 * cb; __builtin_nontemporal_store(o, &y[base + 6 * HW4 + 64]);
    o = a7 + P8 * ca; __builtin_nontemporal_store(o, &y[base + 7 * HW4]);
    o = b7 + P8 * cb; __builtin_nontemporal_store(o, &y[base + 7 * HW4 + 64]);
}

extern "C" void kernel_launch(void* const* d_in, const int* in_sizes, int n_in,
                              void* d_out, int out_size, void* d_ws, size_t ws_size,
                              hipStream_t stream) {
    const vf4* x = (const vf4*)d_in[0];
    vf4*       y = (vf4*)d_out;
    const int chains = 12 * HW4;                 // 196,608
    const int grid   = chains / CPB;             // 1536 blocks, 256 thr each
    recfilt_kernel<<<grid, 256, 0, stream>>>(x, y);
}

// Round 7
// 166.856 us; speedup vs baseline: 1.0159x; 1.0159x over previous
//
#include <hip/hip_runtime.h>

// Problem: y[b,c,0,h,w] = x[b,c,0,h,w]
//          y[b,c,n,h,w] = 0.3*x[b,c,n,h,w] + 0.7*y[b,c,n-1,h,w]
// Shapes: x,y = [4, 3, 32, 256, 256] fp32. Recurrence along axis 2 (N=32).
//
// v7 = v5 verbatim (final revert; best measured variant, 167.57 us total /
// ~52 us dispatch). Session falsification matrix:
//   v2 4x-parallel segmented scan  -> -4 us   (occupancy not binding)
//   v3 launch_bounds/32b/NT-stores -> +-0     (VGPR, store policy not binding)
//   v4 shuffle closure, persistent,
//      software-pipelined          -> +-0     (issue shape not binding)
//   v5 NT loads + NT stores        -> -8 us   (read-allocation eviction tax: REAL)
//   v6 2 chains/thread, 2KB runs   -> +2 us   (DRAM run-length not binding)
// Ceiling arithmetic: compulsory 201 MB (x read + y write) + ~110 MB poison
// writeback drain (harness fills 402 MB of poison through the 256 MB
// write-back MALL between replays; evidenced by the NT-load delta) ~= 320 MB
// real DRAM traffic @ 6.3 TB/s achievable = 49-52 us = measured dispatch.
// The kernel is at the environmental memory floor; remaining dur_us is
// fixed harness overhead (~115 us of fills/reset per iteration).
//
// Structure: segmented scan, 4 segs x 8 frames, LDS carry closure:
//   carry(s) = e[s-1] + 0.7^8*e[s-2] + 0.7^16*e[s-3]
//   y[n]     = p[n] + 0.7^(n+1)*carry   (seg 0: true IC y[0]=x[0], carry=0)
// absmax 0.0078125 (verified passing since v2).

typedef float vf4 __attribute__((ext_vector_type(4)));

constexpr int   NFR = 32;               // frames
constexpr int   HW4 = (256 * 256) / 4;  // float4 per frame-plane (16384 = 2^14)
constexpr int   FPS = 8;                // frames per segment
constexpr int   CPB = 64;               // chains per block
constexpr float WF  = 0.3f;
constexpr float OMW = 0.7f;

constexpr float P1  = 0.7f;
constexpr float P2  = P1 * 0.7f;
constexpr float P3  = P2 * 0.7f;
constexpr float P4  = P3 * 0.7f;
constexpr float P5  = P4 * 0.7f;
constexpr float P6  = P5 * 0.7f;
constexpr float P7  = P6 * 0.7f;
constexpr float P8  = P7 * 0.7f;
constexpr float P16 = P8 * P8;

__global__ __launch_bounds__(256, 8) void recfilt_kernel(const vf4* __restrict__ x,
                                                         vf4* __restrict__ y) {
    const int tid = threadIdx.x;
    const int c   = tid & (CPB - 1);   // chain slot within block
    const int seg = tid >> 6;          // 0..3, wave-uniform
    const int q   = blockIdx.x * CPB + c;      // global chain id [0, 196608)
    const int bc  = q >> 14;                   // q / HW4
    const int hw  = q & (HW4 - 1);             // q % HW4
    const int base = bc * (NFR * HW4) + seg * (FPS * HW4) + hw;   // int32 ok (max 6.29M)

    // ---- 8 independent nontemporal frame loads up front ----
    vf4 v0 = __builtin_nontemporal_load(&x[base + 0 * HW4]);
    vf4 v1 = __builtin_nontemporal_load(&x[base + 1 * HW4]);
    vf4 v2 = __builtin_nontemporal_load(&x[base + 2 * HW4]);
    vf4 v3 = __builtin_nontemporal_load(&x[base + 3 * HW4]);
    vf4 v4 = __builtin_nontemporal_load(&x[base + 4 * HW4]);
    vf4 v5 = __builtin_nontemporal_load(&x[base + 5 * HW4]);
    vf4 v6 = __builtin_nontemporal_load(&x[base + 6 * HW4]);
    vf4 v7 = __builtin_nontemporal_load(&x[base + 7 * HW4]);

    // ---- local prefix. seg 0 frame 0: y[0]=x[0] (leave v0). seg>0: zero IC ----
    if (seg != 0) v0 *= WF;
    v1 = WF * v1 + OMW * v0;
    v2 = WF * v2 + OMW * v1;
    v3 = WF * v3 + OMW * v2;
    v4 = WF * v4 + OMW * v3;
    v5 = WF * v5 + OMW * v4;
    v6 = WF * v6 + OMW * v5;
    v7 = WF * v7 + OMW * v6;

    // ---- publish segment-end partials, close the carry chain ----
    __shared__ vf4 lend[3][CPB];
    if (seg < 3) lend[seg][c] = v7;
    __syncthreads();

    vf4 carry = (vf4)(0.0f);
    if (seg == 1) {
        carry = lend[0][c];
    } else if (seg == 2) {
        carry = lend[1][c] + P8 * lend[0][c];
    } else if (seg == 3) {
        carry = (lend[2][c] + P8 * lend[1][c]) + P16 * lend[0][c];
    }

    // ---- y[n] = p[n] + 0.7^(n+1) * carry ; nontemporal stores ----
    vf4 o0 = v0 + P1 * carry;  __builtin_nontemporal_store(o0, &y[base + 0 * HW4]);
    vf4 o1 = v1 + P2 * carry;  __builtin_nontemporal_store(o1, &y[base + 1 * HW4]);
    vf4 o2 = v2 + P3 * carry;  __builtin_nontemporal_store(o2, &y[base + 2 * HW4]);
    vf4 o3 = v3 + P4 * carry;  __builtin_nontemporal_store(o3, &y[base + 3 * HW4]);
    vf4 o4 = v4 + P5 * carry;  __builtin_nontemporal_store(o4, &y[base + 4 * HW4]);
    vf4 o5 = v5 + P6 * carry;  __builtin_nontemporal_store(o5, &y[base + 5 * HW4]);
    vf4 o6 = v6 + P7 * carry;  __builtin_nontemporal_store(o6, &y[base + 6 * HW4]);
    vf4 o7 = v7 + P8 * carry;  __builtin_nontemporal_store(o7, &y[base + 7 * HW4]);
}

extern "C" void kernel_launch(void* const* d_in, const int* in_sizes, int n_in,
                              void* d_out, int out_size, void* d_ws, size_t ws_size,
                              hipStream_t stream) {
    const vf4* x = (const vf4*)d_in[0];
    vf4*       y = (vf4*)d_out;
    const int chains = 12 * HW4;                 // 196,608
    const int grid   = chains / CPB;             // 3072 blocks, 256 thr each
    recfilt_kernel<<<grid, 256, 0, stream>>>(x, y);
}